// Round 1
// baseline (145.531 us; speedup 1.0000x reference)
//
#include <hip/hip_runtime.h>
#include <hip/hip_bf16.h>

#define NB   32
#define CIN  128
#define COUT 256
#define HH   56
#define WW   56

typedef __attribute__((ext_vector_type(8))) short short8;   // 8 bf16 (4 VGPRs)
typedef __attribute__((ext_vector_type(4))) float f32x4;    // MFMA accumulator

// round-to-nearest-even fp32 -> bf16 (raw u16)
__device__ __forceinline__ unsigned short f2bf(float f) {
    unsigned int u = __builtin_bit_cast(unsigned int, f);
    u = u + 0x7fffu + ((u >> 16) & 1u);
    return (unsigned short)(u >> 16);
}

// ---------------------------------------------------------------------------
// Pre-pass 1: x NCHW f32 -> xt NHWC bf16  (xt[n][h][w][c])
// One block per (n,h). Coalesced reads along w, contiguous bf16x2 writes along c.
// ---------------------------------------------------------------------------
__global__ __launch_bounds__(256) void xpose_kernel(const float* __restrict__ x,
                                                    unsigned short* __restrict__ xt) {
    __shared__ float tile[CIN][WW + 1];   // +1 pad: conflict-free col reads
    const int h = blockIdx.x, n = blockIdx.y;
    const float* src = x + ((size_t)n * CIN * HH + h) * WW;   // x[n][0][h][0]
    for (int i = threadIdx.x; i < CIN * WW; i += 256) {
        int c = i / WW, w = i - c * WW;           // consecutive tid -> consecutive w
        tile[c][w] = src[(size_t)c * HH * WW + w];
    }
    __syncthreads();
    unsigned short* dst = xt + (size_t)(n * HH + h) * WW * CIN;
    for (int i = threadIdx.x; i < WW * (CIN / 2); i += 256) {
        int w = i / (CIN / 2), cp = i - w * (CIN / 2);
        unsigned int lo = f2bf(tile[2 * cp][w]);
        unsigned int hi = f2bf(tile[2 * cp + 1][w]);
        *(unsigned int*)&dst[w * CIN + 2 * cp] = lo | (hi << 16);
    }
}

// ---------------------------------------------------------------------------
// Pre-pass 2: w OIHW f32 -> wt [tap][o][c] bf16   (tap = kh*3+kw)
// ---------------------------------------------------------------------------
__global__ __launch_bounds__(256) void wpose_kernel(const float* __restrict__ w,
                                                    unsigned short* __restrict__ wt) {
    int g = blockIdx.x * 256 + threadIdx.x;     // g = (t*COUT + o)*CIN + c
    if (g >= 9 * COUT * CIN) return;
    int c = g & (CIN - 1);
    int o = (g >> 7) & (COUT - 1);
    int t = g >> 15;
    wt[g] = f2bf(w[(size_t)o * CIN * 9 + c * 9 + t]);
}

// ---------------------------------------------------------------------------
// Main conv: implicit GEMM, one block per (n,h) output row.
// Tile: 256 (Cout) x 64 (w; 56 valid). 8 waves = 4(M) x 2(N), each wave 64x32,
// fragments 4x2 of 16x16, mfma_f32_16x16x32_bf16, K = 9 taps * 4 * 32 chans.
// LDS rows padded to 40 shorts (80 B stride) -> bank-starts spread, ~2-way max.
// ---------------------------------------------------------------------------
#define AP 40   // padded row length (shorts) for 32-element K slices

__global__ __launch_bounds__(512) void conv_mfma_kernel(
        const unsigned short* __restrict__ xt,
        const unsigned short* __restrict__ wt,
        const float* __restrict__ bias,
        float* __restrict__ out) {
    __shared__ unsigned short ldsA[COUT * AP];  // 256 rows x 32 k (padded)  20.0 KB
    __shared__ unsigned short ldsB[64 * AP];    // 64 w   x 32 k (padded)     5.0 KB

    const int tid  = threadIdx.x;
    const int h    = blockIdx.x, n = blockIdx.y;
    const int wid  = tid >> 6, lane = tid & 63;
    const int wm   = wid >> 1, wn = wid & 1;    // wave grid 4(M) x 2(N)
    const int g    = lane >> 4, r = lane & 15;

    f32x4 acc[4][2];
    for (int mi = 0; mi < 4; ++mi)
        for (int ni = 0; ni < 2; ++ni)
            for (int v = 0; v < 4; ++v) acc[mi][ni][v] = 0.f;

    for (int t = 0; t < 9; ++t) {
        const int kh = t / 3, kw = t - kh * 3;
        const int hs = h + kh - 1;
        const bool hok = (unsigned)hs < HH;
        const unsigned short* wtap = wt + (size_t)t * COUT * CIN;
        const unsigned short* xrow = xt + (size_t)(n * HH + hs) * WW * CIN;

        for (int cc = 0; cc < 4; ++cc) {
            // ---- stage A: weights [256][32] as 1024 x 16B chunks ----
            for (int ch = tid; ch < 1024; ch += 512) {
                int o = ch >> 2, seg = ch & 3;
                uint4 v = *(const uint4*)&wtap[o * CIN + cc * 32 + seg * 8];
                *(uint4*)&ldsA[o * AP + seg * 8] = v;
            }
            // ---- stage B: x row [64 w][32 c] as 256 x 16B chunks ----
            if (tid < 256) {
                int w = tid >> 2, seg = tid & 3;
                int ws = w + kw - 1;
                uint4 v = {0u, 0u, 0u, 0u};
                if (hok && (unsigned)ws < WW)
                    v = *(const uint4*)&xrow[ws * CIN + cc * 32 + seg * 8];
                *(uint4*)&ldsB[w * AP + seg * 8] = v;
            }
            __syncthreads();

            // ---- compute: 8 MFMAs per wave ----
            short8 a[4], b[2];
            #pragma unroll
            for (int mi = 0; mi < 4; ++mi)
                a[mi] = *(const short8*)&ldsA[(wm * 64 + mi * 16 + r) * AP + g * 8];
            #pragma unroll
            for (int ni = 0; ni < 2; ++ni)
                b[ni] = *(const short8*)&ldsB[(wn * 32 + ni * 16 + r) * AP + g * 8];
            #pragma unroll
            for (int mi = 0; mi < 4; ++mi)
                #pragma unroll
                for (int ni = 0; ni < 2; ++ni)
                    acc[mi][ni] = __builtin_amdgcn_mfma_f32_16x16x32_bf16(
                        a[mi], b[ni], acc[mi][ni], 0, 0, 0);
            __syncthreads();
        }
    }

    // ---- epilogue: D mapping col=lane&15 (w), row=(lane>>4)*4+v (Cout) ----
    for (int mi = 0; mi < 4; ++mi) {
        const int o0 = wm * 64 + mi * 16 + 4 * g;
        for (int ni = 0; ni < 2; ++ni) {
            const int w = wn * 32 + ni * 16 + r;
            if (w < WW) {
                #pragma unroll
                for (int v = 0; v < 4; ++v) {
                    const int o = o0 + v;
                    out[((size_t)(n * COUT + o) * HH + h) * WW + w] =
                        acc[mi][ni][v] + bias[o];
                }
            }
        }
    }
}

// ---------------------------------------------------------------------------
// Fallback: direct fp32 conv (only if workspace is too small for transforms)
// ---------------------------------------------------------------------------
__global__ __launch_bounds__(256) void conv_direct_kernel(
        const float* __restrict__ x, const float* __restrict__ wgt,
        const float* __restrict__ bias, float* __restrict__ out, int total) {
    int idx = blockIdx.x * 256 + threadIdx.x;
    if (idx >= total) return;
    int w = idx % WW; int tquo = idx / WW;
    int h = tquo % HH; tquo /= HH;
    int o = tquo % COUT; int n = tquo / COUT;
    float s = bias[o];
    const float* xp = x + (size_t)n * CIN * HH * WW;
    const float* wp = wgt + (size_t)o * CIN * 9;
    for (int c = 0; c < CIN; ++c) {
        const float* xc = xp + (size_t)c * HH * WW;
        const float* wc = wp + c * 9;
        #pragma unroll
        for (int kh = 0; kh < 3; ++kh) {
            int hh2 = h + kh - 1;
            if ((unsigned)hh2 >= HH) continue;
            #pragma unroll
            for (int kw = 0; kw < 3; ++kw) {
                int ww2 = w + kw - 1;
                if ((unsigned)ww2 >= WW) continue;
                s += xc[hh2 * WW + ww2] * wc[kh * 3 + kw];
            }
        }
    }
    out[idx] = s;
}

extern "C" void kernel_launch(void* const* d_in, const int* in_sizes, int n_in,
                              void* d_out, int out_size, void* d_ws, size_t ws_size,
                              hipStream_t stream) {
    const float* x  = (const float*)d_in[0];   // (32,128,56,56)
    const float* wk = (const float*)d_in[1];   // (256,128,3,3)
    const float* b  = (const float*)d_in[2];   // (256,)
    float* out = (float*)d_out;

    const size_t xt_elems = (size_t)NB * HH * WW * CIN;      // 12,845,056
    const size_t wt_elems = (size_t)9 * COUT * CIN;          // 294,912
    const size_t need = (xt_elems + wt_elems) * sizeof(unsigned short);

    if (ws_size >= need) {
        unsigned short* xt = (unsigned short*)d_ws;
        unsigned short* wt = xt + xt_elems;

        dim3 gx(HH, NB);
        xpose_kernel<<<gx, 256, 0, stream>>>(x, xt);
        wpose_kernel<<<(9 * COUT * CIN + 255) / 256, 256, 0, stream>>>(wk, wt);
        dim3 gc(HH, NB);
        conv_mfma_kernel<<<gc, 512, 0, stream>>>(xt, wt, b, out);
    } else {
        const int total = NB * COUT * HH * WW;
        conv_direct_kernel<<<(total + 255) / 256, 256, 0, stream>>>(x, wk, b, out, total);
    }
}